// Round 5
// baseline (131.218 us; speedup 1.0000x reference)
//
#include <hip/hip_runtime.h>

// Problem constants: B=16384, IN_DIM=1024, D=256, C=100
#define BATCH 16384
#define KDIM  1024
#define DDIM  256
#define CNUM  100
#define CPAD  112

typedef __bf16 bf16x8 __attribute__((ext_vector_type(8)));
typedef float  floatx4 __attribute__((ext_vector_type(4)));

static __device__ __forceinline__ unsigned short f2b(float f) {
    return __builtin_bit_cast(unsigned short, (__bf16)f);
}

// ---------------- prep: W -> frag-major bf16 Wt2, P->bf16 + pnorm2 ----------
// Wt2 layout: element (n, k) with nblk=n>>4, lm=n&15, kblk=k>>5, lq=(k>>3)&3,
// j=k&7 lives at Wt2[(nblk*32 + kblk)*512 + (lq*16+lm)*8 + j].
// => one MFMA B-fragment (16 cols x 32 k) is 64 lanes x 16B CONTIGUOUS.
__global__ __launch_bounds__(256) void prep(const float* __restrict__ W,
                                            const float* __restrict__ P,
                                            unsigned short* __restrict__ Wt2,
                                            unsigned short* __restrict__ Pbf,
                                            float* __restrict__ pnorm2) {
    __shared__ float T[32][33];
    const int bid = blockIdx.x;
    if (bid < 256) {
        const int k0 = (bid & 31) * 32;
        const int n0 = (bid >> 5) * 32;
        const int j  = threadIdx.x & 31;
        const int i0 = threadIdx.x >> 5;
#pragma unroll
        for (int l = 0; l < 4; ++l) {
            int i = i0 + l * 8;
            T[i][j] = W[(k0 + i) * DDIM + n0 + j];   // T[k-local][n-local]
        }
        __syncthreads();
        if (threadIdx.x < 128) {
            const int l  = threadIdx.x & 63;
            const int fn = threadIdx.x >> 6;          // which 16-col frag (0..1)
            const int lm = l & 15, lq = l >> 4;
            bf16x8 v;
#pragma unroll
            for (int jj = 0; jj < 8; ++jj)
                v[jj] = (__bf16)T[lq * 8 + jj][fn * 16 + lm];
            const int nblk = (n0 >> 4) + fn;
            const int kblk = k0 >> 5;
            *(bf16x8*)&Wt2[(nblk * 32 + kblk) * 512 + l * 8] = v;
        }
    } else {
        const int wave = threadIdx.x >> 6;
        const int lane = threadIdx.x & 63;
        const int c = (bid - 256) * 4 + wave;
        float s = 0.f;
#pragma unroll
        for (int jj = 0; jj < 4; ++jj) {
            int d = jj * 64 + lane;
            float v = (c < CNUM) ? P[c * DDIM + d] : 0.f;
            Pbf[c * DDIM + d] = f2b(v);
            s += v * v;
        }
#pragma unroll
        for (int m = 1; m < 64; m <<= 1) s += __shfl_xor(s, m, 64);
        if (lane == 0) pnorm2[c] = s;
    }
}

// ---------------- fused main -------------------------------------------------
// BM=64, grid 256 (1 block/CU), 256 thr / 4 waves, BK=64.
// BARRIER-FREE, LDS-FREE K-loop: each wave loads its MFMA A-fragments DIRECTLY
// from row-major f32 x (the frag layout — lane(lm,lq) holds rows lm+16g,
// k=(kf*4+lq)*8..+8 — maps to 2x dwordx4 per frag, 16 rows x 128B contiguous
// per instr pair; the 16KB A-tile is read by all 4 waves but fits L1).
// f32->bf16 conversion rides the VALU pipe under the MFMA shadow.
// B comes from L2-hot frag-major Wt2 as before. Both A and B are prefetched a
// full KSTEP ahead in registers (compiler-counted vmcnt, never drained, no
// s_barrier until the epilogue). 1 wave/SIMD + launch_bounds(256,1) -> up to
// 512 VGPRs available; working set ~300 regs, no spill expected.
#define KBODY(KK, QC, BCr, QN, BN)                                             \
    {                                                                          \
        const int kb_ = (KK) >> 5;                                             \
        /* issue next-KSTEP loads first (QN regs are dead here) */             \
        if ((KK) + 64 < KDIM) {                                                \
            _Pragma("unroll")                                                  \
            for (int i = 0; i < 8; ++i) {                                      \
                const int g = i & 3, kf = i >> 2;                              \
                QN[2 * i]     = *(const floatx4*)(gAr[g] + (KK) + 64 + kf * 32);     \
                QN[2 * i + 1] = *(const floatx4*)(gAr[g] + (KK) + 64 + kf * 32 + 4); \
            }                                                                  \
            _Pragma("unroll")                                                  \
            for (int kf = 0; kf < 2; ++kf) {                                   \
                _Pragma("unroll")                                              \
                for (int f = 0; f < 4; ++f)                                    \
                    BN[kf * 4 + f] = *(const bf16x8*)(gB + f * 16384 +         \
                                                      (kb_ + 2 + kf) * 512);   \
            }                                                                  \
        }                                                                      \
        /* convert this KSTEP's A f32 -> bf16 frags (waits on QC's loads) */   \
        bf16x8 af[8];                                                          \
        _Pragma("unroll")                                                      \
        for (int i = 0; i < 8; ++i) {                                          \
            _Pragma("unroll")                                                  \
            for (int j = 0; j < 4; ++j) {                                      \
                af[i][j]     = (__bf16)QC[2 * i][j];                           \
                af[i][4 + j] = (__bf16)QC[2 * i + 1][j];                       \
            }                                                                  \
        }                                                                      \
        _Pragma("unroll")                                                      \
        for (int kf = 0; kf < 2; ++kf) {                                       \
            _Pragma("unroll")                                                  \
            for (int f = 0; f < 4; ++f) {                                      \
                _Pragma("unroll")                                              \
                for (int g = 0; g < 4; ++g)                                    \
                    acc[g][f] = __builtin_amdgcn_mfma_f32_16x16x32_bf16(       \
                        af[kf * 4 + g], BCr[kf * 4 + f], acc[g][f], 0, 0, 0);  \
            }                                                                  \
        }                                                                      \
    }

__global__ __launch_bounds__(256, 1) void fused_main(
    const float* __restrict__ x, const float* __restrict__ bias,
    const unsigned short* __restrict__ Wt2, const unsigned short* __restrict__ Pbf,
    const float* __restrict__ pnorm2, float* __restrict__ out)
{
    __shared__ unsigned short Zs[16896];   // epilogue-only: [64][264] bf16
    __shared__ float rn2[4][64];

    const int tid  = threadIdx.x;
    const int wave = tid >> 6;
    const int lane = tid & 63;
    const int lm   = lane & 15;
    const int lq   = lane >> 4;
    const int r0   = blockIdx.x * 64;

    // A fragment row bases: 4 m-groups (rows r0 + g*16 + lm), k base lq*8
    const float* gAr[4];
#pragma unroll
    for (int g = 0; g < 4; ++g)
        gAr[g] = x + (size_t)(r0 + g * 16 + lm) * KDIM + lq * 8;

    // B: frag-major Wt2; this wave's 4 col-frags start at nblk = wave*4
    const unsigned short* gB = Wt2 + wave * 4 * 16384 + lane * 8;

    floatx4 acc[4][4];
#pragma unroll
    for (int g = 0; g < 4; ++g)
#pragma unroll
        for (int f = 0; f < 4; ++f) { acc[g][f][0]=0.f; acc[g][f][1]=0.f; acc[g][f][2]=0.f; acc[g][f][3]=0.f; }

    floatx4 qa[16], qb[16];   // A f32 ping-pong (statically indexed in unrolls)
    bf16x8  bc[8],  bn[8];    // B bf16 ping-pong

    // ---- prologue: issue KSTEP-0 loads ----
#pragma unroll
    for (int i = 0; i < 8; ++i) {
        const int g = i & 3, kf = i >> 2;
        qa[2 * i]     = *(const floatx4*)(gAr[g] + kf * 32);
        qa[2 * i + 1] = *(const floatx4*)(gAr[g] + kf * 32 + 4);
    }
#pragma unroll
    for (int kf = 0; kf < 2; ++kf)
#pragma unroll
        for (int f = 0; f < 4; ++f)
            bc[kf * 4 + f] = *(const bf16x8*)(gB + f * 16384 + kf * 512);

    for (int kk0 = 0; kk0 < KDIM; kk0 += 128) {
        KBODY(kk0,      qa, bc, qb, bn)
        KBODY(kk0 + 64, qb, bn, qa, bc)
    }

    // ---- bias ----
#pragma unroll
    for (int f = 0; f < 4; ++f) {
        float bb = bias[wave * 64 + f * 16 + lm];
#pragma unroll
        for (int g = 0; g < 4; ++g)
#pragma unroll
            for (int r = 0; r < 4; ++r) acc[g][f][r] += bb;
    }

    // ---- partial row norms over this wave's 64 cols ----
#pragma unroll
    for (int g = 0; g < 4; ++g) {
        float s0 = 0.f, s1 = 0.f, s2 = 0.f, s3 = 0.f;
#pragma unroll
        for (int f = 0; f < 4; ++f) {
            s0 += acc[g][f][0] * acc[g][f][0];
            s1 += acc[g][f][1] * acc[g][f][1];
            s2 += acc[g][f][2] * acc[g][f][2];
            s3 += acc[g][f][3] * acc[g][f][3];
        }
#pragma unroll
        for (int m = 1; m < 16; m <<= 1) {
            s0 += __shfl_xor(s0, m, 64);
            s1 += __shfl_xor(s1, m, 64);
            s2 += __shfl_xor(s2, m, 64);
            s3 += __shfl_xor(s3, m, 64);
        }
        if (lm == 0) {
            int rl = g * 16 + lq * 4;
            rn2[wave][rl + 0] = s0;
            rn2[wave][rl + 1] = s1;
            rn2[wave][rl + 2] = s2;
            rn2[wave][rl + 3] = s3;
        }
    }

    // ---- Z -> LDS bf16 for GEMM2 ----
#pragma unroll
    for (int g = 0; g < 4; ++g)
#pragma unroll
        for (int f = 0; f < 4; ++f) {
            int col = wave * 64 + f * 16 + lm;
#pragma unroll
            for (int r = 0; r < 4; ++r)
                Zs[(g * 16 + lq * 4 + r) * 264 + col] = f2b(acc[g][f][r]);
        }
    __syncthreads();

    // ---- GEMM2: D2[class][row] = P @ Z^T, M=112 N=64 K=256 ----
#pragma unroll
    for (int t = 0; t < 2; ++t) {
        const int ct = wave * 2 + t;
        if (ct < 7) {
            floatx4 acc2[4];
#pragma unroll
            for (int nf = 0; nf < 4; ++nf) { acc2[nf][0]=0.f; acc2[nf][1]=0.f; acc2[nf][2]=0.f; acc2[nf][3]=0.f; }
            const unsigned short* gP = Pbf + (ct * 16 + lm) * DDIM + lq * 8;
#pragma unroll
            for (int ks = 0; ks < 8; ++ks) {
                bf16x8 ap = *(const bf16x8*)(gP + ks * 32);   // L2-hot
#pragma unroll
                for (int nf = 0; nf < 4; ++nf) {
                    bf16x8 bz = *(const bf16x8*)&Zs[(nf * 16 + lm) * 264 + ks * 32 + lq * 8];
                    acc2[nf] = __builtin_amdgcn_mfma_f32_16x16x32_bf16(ap, bz, acc2[nf], 0, 0, 0);
                }
            }
            int c0 = ct * 16 + lq * 4;
            if (c0 < CNUM) {
                floatx4 pn = *(const floatx4*)(pnorm2 + c0);
#pragma unroll
                for (int nf = 0; nf < 4; ++nf) {
                    int rl = nf * 16 + lm;
                    float rn = rn2[0][rl] + rn2[1][rl] + rn2[2][rl] + rn2[3][rl];
                    floatx4 o;
#pragma unroll
                    for (int r = 0; r < 4; ++r)
                        o[r] = (2.f * acc2[nf][r] - rn - pn[r]) * (1.f / 256.f);
                    *(floatx4*)&out[(r0 + rl) * CNUM + c0] = o;
                }
            }
        }
    }
}

extern "C" void kernel_launch(void* const* d_in, const int* in_sizes, int n_in,
                              void* d_out, int out_size, void* d_ws, size_t ws_size,
                              hipStream_t stream) {
    const float* x = (const float*)d_in[0];
    const float* W = (const float*)d_in[1];
    const float* b = (const float*)d_in[2];
    const float* P = (const float*)d_in[3];
    float* out = (float*)d_out;

    unsigned short* Wt2 = (unsigned short*)d_ws;
    unsigned short* Pbf = Wt2 + KDIM * DDIM;
    float* pn2 = (float*)(Pbf + CPAD * DDIM);

    prep<<<256 + CPAD / 4, 256, 0, stream>>>(W, P, Wt2, Pbf, pn2);
    fused_main<<<BATCH / 64, 256, 0, stream>>>(x, b, Wt2, Pbf, pn2, out);
}

// Round 6
// 112.055 us; speedup vs baseline: 1.1710x; 1.1710x over previous
//
#include <hip/hip_runtime.h>

// Problem constants: B=16384, IN_DIM=1024, D=256, C=100
#define BATCH 16384
#define KDIM  1024
#define DDIM  256
#define CNUM  100
#define CPAD  112
#define RSTR  72   // Rs row stride (floats): mult of 4 for b128, 4-way bank max

typedef __bf16 bf16x8 __attribute__((ext_vector_type(8)));
typedef float  floatx4 __attribute__((ext_vector_type(4)));

static __device__ __forceinline__ unsigned short f2b(float f) {
    return __builtin_bit_cast(unsigned short, (__bf16)f);
}

// ---------------- prep: W -> frag-major bf16 Wt2, P->bf16 + pnorm2 ----------
// Wt2 layout: element (n, k) with nblk=n>>4, lm=n&15, kblk=k>>5, lq=(k>>3)&3,
// j=k&7 lives at Wt2[(nblk*32 + kblk)*512 + (lq*16+lm)*8 + j].
__global__ __launch_bounds__(256) void prep(const float* __restrict__ W,
                                            const float* __restrict__ P,
                                            unsigned short* __restrict__ Wt2,
                                            unsigned short* __restrict__ Pbf,
                                            float* __restrict__ pnorm2) {
    __shared__ float T[32][33];
    const int bid = blockIdx.x;
    if (bid < 256) {
        const int k0 = (bid & 31) * 32;
        const int n0 = (bid >> 5) * 32;
        const int j  = threadIdx.x & 31;
        const int i0 = threadIdx.x >> 5;
#pragma unroll
        for (int l = 0; l < 4; ++l) {
            int i = i0 + l * 8;
            T[i][j] = W[(k0 + i) * DDIM + n0 + j];   // T[k-local][n-local]
        }
        __syncthreads();
        if (threadIdx.x < 128) {
            const int l  = threadIdx.x & 63;
            const int fn = threadIdx.x >> 6;
            const int lm = l & 15, lq = l >> 4;
            bf16x8 v;
#pragma unroll
            for (int jj = 0; jj < 8; ++jj)
                v[jj] = (__bf16)T[lq * 8 + jj][fn * 16 + lm];
            const int nblk = (n0 >> 4) + fn;
            const int kblk = k0 >> 5;
            *(bf16x8*)&Wt2[(nblk * 32 + kblk) * 512 + l * 8] = v;
        }
    } else {
        const int wave = threadIdx.x >> 6;
        const int lane = threadIdx.x & 63;
        const int c = (bid - 256) * 4 + wave;
        float s = 0.f;
#pragma unroll
        for (int jj = 0; jj < 4; ++jj) {
            int d = jj * 64 + lane;
            float v = (c < CNUM) ? P[c * DDIM + d] : 0.f;
            Pbf[c * DDIM + d] = f2b(v);
            s += v * v;
        }
#pragma unroll
        for (int m = 1; m < 64; m <<= 1) s += __shfl_xor(s, m, 64);
        if (lane == 0) pnorm2[c] = s;
    }
}

// ---------------- fused main -------------------------------------------------
// SPLIT-K, 8 waves (512 thr) = 2 waves/SIMD, BM=64, grid 256 (1 block/CU).
// Round-5 proved the regime is LATENCY-bound (MfmaUtil 6%, all pipes idle at
// 1 wave/SIMD); round-4 proved traffic matters. This keeps round-4's traffic
// (x 256KB/block, B 512KB/block, each frag read once) but doubles TLP:
// wave (kh, wn) computes rows 0..63 x cols wn*64..+64 over K-half kh (8 KSTEPs
// of 64). acc[4][4] keeps 4x B-register reuse. Two 64x64 A-tiles (one per
// K-half) staged in LDS per KSTEP, double-buffered; x prefetch depth-2
// ping-pong; B depth-1 from L2-hot frag-major Wt2. Barrier = lgkmcnt(0)+
// s_barrier, vmcnt never drained. Epilogue: f32 LDS reduce of the two
// K-halves (stride-RSTR pad), then bias/norms/Zs/GEMM2 as before.
#define KSTEP(KK, CUR, NXT, P0, P1, P2, P3)                                    \
    {                                                                          \
        const unsigned short* As_c = U16 + (CUR) * 8192 + kh * 4096;           \
        const int kb_ = (KK) >> 5;                                             \
        if ((KK) + 64 < 512) {                                                 \
            _Pragma("unroll")                                                  \
            for (int kf = 0; kf < 2; ++kf) {                                   \
                _Pragma("unroll")                                              \
                for (int f = 0; f < 4; ++f)                                    \
                    b[NXT][kf * 4 + f] = *(const bf16x8*)(gB + f * 16384 +     \
                                                     (kb_ + 2 + kf) * 512);    \
            }                                                                  \
            bf16x8 ha;                                                         \
            ha[0] = (__bf16)P0[0]; ha[1] = (__bf16)P0[1];                      \
            ha[2] = (__bf16)P0[2]; ha[3] = (__bf16)P0[3];                      \
            ha[4] = (__bf16)P1[0]; ha[5] = (__bf16)P1[1];                      \
            ha[6] = (__bf16)P1[2]; ha[7] = (__bf16)P1[3];                      \
            *(bf16x8*)&U16[(NXT) * 8192 + ldsA] = ha;                          \
            bf16x8 hb;                                                         \
            hb[0] = (__bf16)P2[0]; hb[1] = (__bf16)P2[1];                      \
            hb[2] = (__bf16)P2[2]; hb[3] = (__bf16)P2[3];                      \
            hb[4] = (__bf16)P3[0]; hb[5] = (__bf16)P3[1];                      \
            hb[6] = (__bf16)P3[2]; hb[7] = (__bf16)P3[3];                      \
            *(bf16x8*)&U16[(NXT) * 8192 + 4096 + ldsA] = hb;                   \
            if ((KK) + 192 < 512) {                                            \
                P0 = *(const floatx4*)(gA + (KK) + 192);                       \
                P1 = *(const floatx4*)(gA + (KK) + 196);                       \
                P2 = *(const floatx4*)(gA + 512 + (KK) + 192);                 \
                P3 = *(const floatx4*)(gA + 512 + (KK) + 196);                 \
            }                                                                  \
        }                                                                      \
        _Pragma("unroll")                                                      \
        for (int kf = 0; kf < 2; ++kf) {                                       \
            const int sw = kf ? sw1 : sw0;                                     \
            bf16x8 a0 = *(const bf16x8*)&As_c[lm * 64 + sw];                   \
            bf16x8 a1 = *(const bf16x8*)&As_c[(16 + lm) * 64 + sw];            \
            bf16x8 a2 = *(const bf16x8*)&As_c[(32 + lm) * 64 + sw];            \
            bf16x8 a3 = *(const bf16x8*)&As_c[(48 + lm) * 64 + sw];            \
            _Pragma("unroll")                                                  \
            for (int f = 0; f < 4; ++f) {                                      \
                acc[0][f] = __builtin_amdgcn_mfma_f32_16x16x32_bf16(           \
                    a0, b[CUR][kf * 4 + f], acc[0][f], 0, 0, 0);               \
                acc[1][f] = __builtin_amdgcn_mfma_f32_16x16x32_bf16(           \
                    a1, b[CUR][kf * 4 + f], acc[1][f], 0, 0, 0);               \
                acc[2][f] = __builtin_amdgcn_mfma_f32_16x16x32_bf16(           \
                    a2, b[CUR][kf * 4 + f], acc[2][f], 0, 0, 0);               \
                acc[3][f] = __builtin_amdgcn_mfma_f32_16x16x32_bf16(           \
                    a3, b[CUR][kf * 4 + f], acc[3][f], 0, 0, 0);               \
            }                                                                  \
        }                                                                      \
        asm volatile("s_waitcnt lgkmcnt(0)\n\ts_barrier" ::: "memory");        \
    }

__global__ __launch_bounds__(512, 2) void fused_main(
    const float* __restrict__ x, const float* __restrict__ bias,
    const unsigned short* __restrict__ Wt2, const unsigned short* __restrict__ Pbf,
    const float* __restrict__ pnorm2, float* __restrict__ out)
{
    // Union buffer: A dbuf (2 x 2 tiles x 8KB = 32KB) | Rs reduce (4*64*RSTR
    // f32 = 72KB) | Zs epilogue ([64][264] bf16 = 33.8KB). Sequential uses,
    // barrier-separated.
    __shared__ __align__(16) float Ubuf[4 * 64 * RSTR];   // 73728 B
    __shared__ float rn2[4][64];
    unsigned short* U16 = (unsigned short*)Ubuf;
    float* Rs = Ubuf;
    unsigned short* Zs = (unsigned short*)Ubuf;

    const int tid  = threadIdx.x;
    const int wave = tid >> 6;
    const int kh   = wave >> 2;          // K-half: 0 -> k<512, 1 -> k>=512
    const int wn   = wave & 3;           // col-group
    const int lane = tid & 63;
    const int lm   = lane & 15;
    const int lq   = lane >> 4;
    const int r0   = blockIdx.x * 64;

    // A staging: thread -> row tid>>3 (0..63), k-block tid&7; stages BOTH
    // K-half tiles (k=kk+kb*8 and k=512+kk+kb*8), XOR-swizzled slot.
    const int rowA = tid >> 3;
    const int kbA  = tid & 7;
    const float* gA = x + (size_t)(r0 + rowA) * KDIM + kbA * 8;
    const int ldsA = rowA * 64 + ((kbA ^ (rowA & 7)) * 8);

    // B: frag-major Wt2; wave's cols at nblk=wn*4, K-half offset kh*16 kblks
    const unsigned short* gB = Wt2 + wn * 65536 + kh * 8192 + lane * 8;

    // A frag-read swizzle (rows lm+16g -> low3 bits lm&7)
    const int sw0 = ((0 * 4 + lq) ^ (lm & 7)) * 8;
    const int sw1 = ((1 * 4 + lq) ^ (lm & 7)) * 8;

    floatx4 acc[4][4];
#pragma unroll
    for (int g = 0; g < 4; ++g)
#pragma unroll
        for (int f = 0; f < 4; ++f) { acc[g][f][0]=0.f; acc[g][f][1]=0.f; acc[g][f][2]=0.f; acc[g][f][3]=0.f; }

    bf16x8 b[2][8];   // [buf][kf*4+f] — statically indexed via KSTEP macro

    // ---- prologue: stage buf0 (kk=0, both halves); B kk=0; x pf 64 & 128 --
    {
        floatx4 q0 = *(const floatx4*)(gA);
        floatx4 q1 = *(const floatx4*)(gA + 4);
        floatx4 q2 = *(const floatx4*)(gA + 512);
        floatx4 q3 = *(const floatx4*)(gA + 516);
        bf16x8 ha;
        ha[0] = (__bf16)q0[0]; ha[1] = (__bf16)q0[1];
        ha[2] = (__bf16)q0[2]; ha[3] = (__bf16)q0[3];
        ha[4] = (__bf16)q1[0]; ha[5] = (__bf16)q1[1];
        ha[6] = (__bf16)q1[2]; ha[7] = (__bf16)q1[3];
        *(bf16x8*)&U16[ldsA] = ha;
        bf16x8 hb;
        hb[0] = (__bf16)q2[0]; hb[1] = (__bf16)q2[1];
        hb[2] = (__bf16)q2[2]; hb[3] = (__bf16)q2[3];
        hb[4] = (__bf16)q3[0]; hb[5] = (__bf16)q3[1];
        hb[6] = (__bf16)q3[2]; hb[7] = (__bf16)q3[3];
        *(bf16x8*)&U16[4096 + ldsA] = hb;
    }
#pragma unroll
    for (int kf = 0; kf < 2; ++kf)
#pragma unroll
        for (int f = 0; f < 4; ++f)
            b[0][kf * 4 + f] = *(const bf16x8*)(gB + f * 16384 + kf * 512);
    // depth-2 x prefetch (both halves): pa feeds even KSTEPs, pb odd
    floatx4 pa0 = *(const floatx4*)(gA + 64);
    floatx4 pa1 = *(const floatx4*)(gA + 68);
    floatx4 pa2 = *(const floatx4*)(gA + 576);
    floatx4 pa3 = *(const floatx4*)(gA + 580);
    floatx4 pb0 = *(const floatx4*)(gA + 128);
    floatx4 pb1 = *(const floatx4*)(gA + 132);
    floatx4 pb2 = *(const floatx4*)(gA + 640);
    floatx4 pb3 = *(const floatx4*)(gA + 644);
    asm volatile("s_waitcnt lgkmcnt(0)\n\ts_barrier" ::: "memory");

    for (int kk0 = 0; kk0 < 512; kk0 += 128) {
        KSTEP(kk0,      0, 1, pa0, pa1, pa2, pa3)
        KSTEP(kk0 + 64, 1, 0, pb0, pb1, pb2, pb3)
    }

    // ---- reduce K-halves: kh=1 writes partials, kh=0 accumulates ----
    if (kh == 1) {
#pragma unroll
        for (int g = 0; g < 4; ++g)
#pragma unroll
            for (int f = 0; f < 4; ++f)
                *(floatx4*)&Rs[(wn * 64 + f * 16 + lm) * RSTR + g * 16 + lq * 4] = acc[g][f];
    }
    __syncthreads();
    if (kh == 0) {
#pragma unroll
        for (int g = 0; g < 4; ++g)
#pragma unroll
            for (int f = 0; f < 4; ++f) {
                floatx4 p = *(const floatx4*)&Rs[(wn * 64 + f * 16 + lm) * RSTR + g * 16 + lq * 4];
#pragma unroll
                for (int r = 0; r < 4; ++r) acc[g][f][r] += p[r];
            }
        // ---- bias (once, on the merged sums) ----
#pragma unroll
        for (int f = 0; f < 4; ++f) {
            float bb = bias[wn * 64 + f * 16 + lm];
#pragma unroll
            for (int g = 0; g < 4; ++g)
#pragma unroll
                for (int r = 0; r < 4; ++r) acc[g][f][r] += bb;
        }
        // ---- partial row norms over this wave's 64 cols ----
#pragma unroll
        for (int g = 0; g < 4; ++g) {
            float s0 = 0.f, s1 = 0.f, s2 = 0.f, s3 = 0.f;
#pragma unroll
            for (int f = 0; f < 4; ++f) {
                s0 += acc[g][f][0] * acc[g][f][0];
                s1 += acc[g][f][1] * acc[g][f][1];
                s2 += acc[g][f][2] * acc[g][f][2];
                s3 += acc[g][f][3] * acc[g][f][3];
            }
#pragma unroll
            for (int m = 1; m < 16; m <<= 1) {
                s0 += __shfl_xor(s0, m, 64);
                s1 += __shfl_xor(s1, m, 64);
                s2 += __shfl_xor(s2, m, 64);
                s3 += __shfl_xor(s3, m, 64);
            }
            if (lm == 0) {
                int rl = g * 16 + lq * 4;
                rn2[wn][rl + 0] = s0;
                rn2[wn][rl + 1] = s1;
                rn2[wn][rl + 2] = s2;
                rn2[wn][rl + 3] = s3;
            }
        }
    }
    __syncthreads();   // all Rs reads done; Zs (same memory) now safe

    // ---- Z -> LDS bf16 for GEMM2 (kh=0 waves hold the merged Z) ----
    if (kh == 0) {
#pragma unroll
        for (int g = 0; g < 4; ++g)
#pragma unroll
            for (int f = 0; f < 4; ++f) {
                int col = wn * 64 + f * 16 + lm;
#pragma unroll
                for (int r = 0; r < 4; ++r)
                    Zs[(g * 16 + lq * 4 + r) * 264 + col] = f2b(acc[g][f][r]);
            }
    }
    __syncthreads();

    // ---- GEMM2: D2[class][row] = P @ Z^T, M=112 N=64 K=256; 1 ct/wave ----
    {
        const int ct = wave;
        if (ct < 7) {
            floatx4 acc2[4];
#pragma unroll
            for (int nf = 0; nf < 4; ++nf) { acc2[nf][0]=0.f; acc2[nf][1]=0.f; acc2[nf][2]=0.f; acc2[nf][3]=0.f; }
            const unsigned short* gP = Pbf + (ct * 16 + lm) * DDIM + lq * 8;
#pragma unroll
            for (int ks = 0; ks < 8; ++ks) {
                bf16x8 ap = *(const bf16x8*)(gP + ks * 32);   // L2-hot
#pragma unroll
                for (int nf = 0; nf < 4; ++nf) {
                    bf16x8 bz = *(const bf16x8*)&Zs[(nf * 16 + lm) * 264 + ks * 32 + lq * 8];
                    acc2[nf] = __builtin_amdgcn_mfma_f32_16x16x32_bf16(ap, bz, acc2[nf], 0, 0, 0);
                }
            }
            int c0 = ct * 16 + lq * 4;
            if (c0 < CNUM) {
                floatx4 pn = *(const floatx4*)(pnorm2 + c0);
#pragma unroll
                for (int nf = 0; nf < 4; ++nf) {
                    int rl = nf * 16 + lm;
                    float rn = rn2[0][rl] + rn2[1][rl] + rn2[2][rl] + rn2[3][rl];
                    floatx4 o;
#pragma unroll
                    for (int r = 0; r < 4; ++r)
                        o[r] = (2.f * acc2[nf][r] - rn - pn[r]) * (1.f / 256.f);
                    *(floatx4*)&out[(r0 + rl) * CNUM + c0] = o;
                }
            }
        }
    }
}

extern "C" void kernel_launch(void* const* d_in, const int* in_sizes, int n_in,
                              void* d_out, int out_size, void* d_ws, size_t ws_size,
                              hipStream_t stream) {
    const float* x = (const float*)d_in[0];
    const float* W = (const float*)d_in[1];
    const float* b = (const float*)d_in[2];
    const float* P = (const float*)d_in[3];
    float* out = (float*)d_out;

    unsigned short* Wt2 = (unsigned short*)d_ws;
    unsigned short* Pbf = Wt2 + KDIM * DDIM;
    float* pn2 = (float*)(Pbf + CPAD * DDIM);

    prep<<<256 + CPAD / 4, 256, 0, stream>>>(W, P, Wt2, Pbf, pn2);
    fused_main<<<BATCH / 64, 512, 0, stream>>>(x, b, Wt2, Pbf, pn2, out);
}